// Round 1
// baseline (252.249 us; speedup 1.0000x reference)
//
#include <hip/hip_runtime.h>

// NonMaxSuppression: 3x3 local max + thr>=0.6 + 10px border -> ordered (y,x) coords.
// Input fixed: (16,1,1536,1536) fp32.
// Pass1: barrier-free rolling-register NMS. Block = 32 rows x 1536 px, thread = 4 cols.
//        Two unaligned (dword-aligned) float4 loads/row give the 6-wide halo window;
//        separable v_max3 vertical window rolls in registers. u64 masks + block counts.
// Pass2 (fused scan+scatter): 768 blocks x 768 threads; each block self-computes its
//        exclusive offset from the 768 counts (1 count/thread + 2-level reduce), then
//        mask replay + ordered (y,x) scatter. No separate 1-block scan kernel.
#define W 1536
#define H 1536
#define NB 16
#define NROWS (NB * H)              // 24576
#define SH 32                       // output rows per pass1 block
#define NBLK1 (NROWS / SH)          // 768
#define BLOCK1 384                  // 1536/4 cols per thread-row
#define CPR 24                      // u64 chunks per row
#define NMASK (NROWS * CPR)         // 589824 u64 = 4.72 MB
#define BLOCK2 (SH * CPR)           // 768 chunks per strip = threads of pass2
#define REP_THR 0.6f

__device__ __forceinline__ float max3f(float a, float b, float c) {
    return fmaxf(fmaxf(a, b), c);  // v_max3_f32
}

// dword-aligned (not 16B-aligned) float4 load
__device__ __forceinline__ float4 ld4u(const float* p) {
    float4 r;
    __builtin_memcpy(&r, p, 16);
    return r;
}

__global__ __launch_bounds__(BLOCK1) void nms_pass1(const float* __restrict__ in,
                                                    unsigned long long* __restrict__ masks,
                                                    unsigned int* __restrict__ counts) {
    const int t = threadIdx.x;
    const int lane = t & 63;
    const int wv = t >> 6;
    const int blk = blockIdx.x;
    const int r0 = blk * SH;                 // first output row (global, = img*H + ytile*SH)
    const int ytile = blk % (H / SH);        // strip index within image

    // column windows: va covers cols 4t-1..4t+2, vb covers 4t+1..4t+4 (clamped at edges;
    // clamped lanes produce garbage only where the x-border mask kills the result)
    const int ca = (t == 0) ? 0 : 4 * t - 1;
    const int cb = (t == BLOCK1 - 1) ? 4 * t : 4 * t + 1;

    // x-border nibble mask, valid x in [10, 1526)
    unsigned colm = 0xFu;
    if (t <= 1) colm = 0u;
    else if (t == 2) colm = 0xCu;
    if (t >= 382) colm = 0u;
    else if (t == 381) colm = 0x3u;

    auto rowp = [&](int i) {                 // input row rel i (rel 0 = r0-1), clamped
        int ir = r0 - 1 + i;
        ir = ir < 0 ? 0 : (ir >= NROWS ? NROWS - 1 : ir);
        return in + (size_t)ir * W;
    };

    // prologue: rows rel 0,1 and prefetch rel 2
    float4 va0 = ld4u(rowp(0) + ca), vb0 = ld4u(rowp(0) + cb);
    float4 va1 = ld4u(rowp(1) + ca), vb1 = ld4u(rowp(1) + cb);
    float4 vaN = ld4u(rowp(2) + ca), vbN = ld4u(rowp(2) + cb);

    float4 hA, hB, ctrB;
    hA.x = max3f(va0.x, va0.y, va0.z);
    hA.y = max3f(va0.y, va0.z, va0.w);
    hA.z = max3f(vb0.x, vb0.y, vb0.z);
    hA.w = max3f(vb0.y, vb0.z, vb0.w);
    hB.x = max3f(va1.x, va1.y, va1.z);
    hB.y = max3f(va1.y, va1.z, va1.w);
    hB.z = max3f(vb1.x, vb1.y, vb1.z);
    hB.w = max3f(vb1.y, vb1.z, vb1.w);
    ctrB.x = va1.y; ctrB.y = va1.z; ctrB.z = va1.w; ctrB.w = vb1.z;

    unsigned cnt = 0;
#pragma unroll
    for (int i = 2; i <= SH + 1; ++i) {
        float4 va = vaN, vb = vbN;
        vaN = ld4u(rowp(i + 1) + ca);        // depth-1 prefetch (clamped; overshoot harmless)
        vbN = ld4u(rowp(i + 1) + cb);
        float4 hC;
        hC.x = max3f(va.x, va.y, va.z);
        hC.y = max3f(va.y, va.z, va.w);
        hC.z = max3f(vb.x, vb.y, vb.z);
        hC.w = max3f(vb.y, vb.z, vb.w);

        const int yloc = ytile * SH + (i - 2);   // image-local y of emitted row
        unsigned nib = 0u;
        if (yloc >= 10 && yloc < H - 10) {
            nib |= (ctrB.x >= fmaxf(max3f(hA.x, hB.x, hC.x), REP_THR)) ? 1u : 0u;
            nib |= (ctrB.y >= fmaxf(max3f(hA.y, hB.y, hC.y), REP_THR)) ? 2u : 0u;
            nib |= (ctrB.z >= fmaxf(max3f(hA.z, hB.z, hC.z), REP_THR)) ? 4u : 0u;
            nib |= (ctrB.w >= fmaxf(max3f(hA.w, hB.w, hC.w), REP_THR)) ? 8u : 0u;
            nib &= colm;
        }
        cnt += __popc(nib);
        // fold 16 lanes' nibbles -> u64 chunk (lane%16==0 stores)
        unsigned x = nib;
        x |= __shfl_down(x, 1, 64) << 4;
        x |= __shfl_down(x, 2, 64) << 8;
        x |= __shfl_down(x, 4, 64) << 16;
        unsigned hi = __shfl_down(x, 8, 64);
        if ((lane & 15) == 0) {
            unsigned long long m64 = (unsigned long long)x | ((unsigned long long)hi << 32);
            masks[(size_t)(r0 + i - 2) * CPR + (t >> 4)] = m64;
        }
        hA = hB; hB = hC;
        ctrB.x = va.y; ctrB.y = va.z; ctrB.z = va.w; ctrB.w = vb.z;
    }

#pragma unroll
    for (int o = 32; o > 0; o >>= 1) cnt += __shfl_down(cnt, o, 64);
    __shared__ unsigned wsum[BLOCK1 / 64];
    if (lane == 0) wsum[wv] = cnt;
    __syncthreads();
    if (t == 0) {
        unsigned s = 0;
#pragma unroll
        for (int k = 0; k < BLOCK1 / 64; ++k) s += wsum[k];
        counts[blk] = s;
    }
}

// Pass 2: fused scan + scatter. One u64 mask chunk per thread (768 = 32 rows x 24 chunks,
// row-major so thread order == spatial order). Block offset = sum of counts[0..blk)
// computed in-block: one count per thread + wave/LDS reduce.
__global__ __launch_bounds__(BLOCK2) void nms_scatter(const unsigned long long* __restrict__ masks,
                                                      const unsigned int* __restrict__ counts,
                                                      int* __restrict__ out, unsigned int K) {
    const int t = threadIdx.x, lane = t & 63, wv = t >> 6;
    const int blk = blockIdx.x;
    unsigned long long bits = masks[(size_t)blk * BLOCK2 + t];
    const unsigned cnt = (unsigned)__popcll(bits);
    unsigned incl = cnt;
#pragma unroll
    for (int o = 1; o < 64; o <<= 1) {
        unsigned u = __shfl_up(incl, o, 64);
        if (lane >= o) incl += u;
    }
    // exclusive block offset: counts[t] for t < blk (blk <= 767 < BLOCK2, so 1 load/thread)
    unsigned part = (t < blk) ? counts[t] : 0u;
#pragma unroll
    for (int o = 32; o > 0; o >>= 1) part += __shfl_down(part, o, 64);
    __shared__ unsigned wtot[BLOCK2 / 64];
    __shared__ unsigned coff[BLOCK2 / 64];
    if (lane == 63) wtot[wv] = incl;
    if (lane == 0) coff[wv] = part;
    __syncthreads();
    unsigned pos = incl - cnt;
#pragma unroll
    for (int k = 0; k < BLOCK2 / 64; ++k) {
        pos += coff[k];
        pos += (k < wv) ? wtot[k] : 0u;
    }
    if (bits) {
        const int y = (blk % (H / SH)) * SH + t / CPR;   // image-local row
        const int x0 = (t % CPR) * 64;
        while (bits) {
            int j = __builtin_ctzll(bits);
            bits &= bits - 1ull;
            if (pos < K) { out[pos] = y; out[K + pos] = x0 + j; }
            ++pos;
        }
    }
}

extern "C" void kernel_launch(void* const* d_in, const int* in_sizes, int n_in,
                              void* d_out, int out_size, void* d_ws, size_t ws_size,
                              hipStream_t stream) {
    const float* in = (const float*)d_in[0];
    int* out = (int*)d_out;
    unsigned long long* masks = (unsigned long long*)d_ws;
    unsigned int* counts = (unsigned int*)((char*)d_ws + (size_t)NMASK * 8);
    const unsigned K = (unsigned)(out_size / 2);

    nms_pass1<<<NBLK1, BLOCK1, 0, stream>>>(in, masks, counts);
    nms_scatter<<<NBLK1, BLOCK2, 0, stream>>>(masks, counts, out, K);
}